// Round 3
// baseline (509.961 us; speedup 1.0000x reference)
//
#include <hip/hip_runtime.h>
#include <cstdint>
#include <cstddef>

#define TOK 16384
#define NE  8192

// output layout (all float32, concatenated): loss | z_q(32,64,512) | perp | enc(16384,8192) | idx(16384)
#define O_ZQ   1
#define O_PERP 1048577
#define O_ENC  1048578
#define O_IDX  135266306

// ---------------------------------------------------------------------------
// K0: per-code s_e (numpy 8-acc pairwise), init packed (~0) and hist (0)
// grid 64 x 256 = 16384 threads
// ---------------------------------------------------------------------------
__global__ __launch_bounds__(256) void k_init(
    const float* __restrict__ emb,
    unsigned long long* __restrict__ packed,
    float* __restrict__ s_e, int* __restrict__ hist) {
  int g = blockIdx.x * 256 + threadIdx.x;
  if (g < NE) {
    const float* ep = emb + (size_t)g * 64;
    float r[8];
#pragma unroll
    for (int j = 0; j < 8; ++j) { float v = ep[j]; r[j] = __fmul_rn(v, v); }
#pragma unroll
    for (int kk = 8; kk < 64; kk += 8)
#pragma unroll
      for (int j = 0; j < 8; ++j) { float v = ep[kk + j]; r[j] = __fadd_rn(r[j], __fmul_rn(v, v)); }
    float s = __fadd_rn(__fadd_rn(__fadd_rn(r[0], r[1]), __fadd_rn(r[2], r[3])),
                        __fadd_rn(__fadd_rn(r[4], r[5]), __fadd_rn(r[6], r[7])));
    s_e[g] = s;
    hist[g] = 0;
  }
  packed[g] = ~0ull;   // g covers 0..16383 == TOK
}

// ---------------------------------------------------------------------------
// K1: search. lane = token; z in VGPRs (loaded once); emb row is wave-uniform
// -> scalar loads (SGPR) -> inner loop has ZERO LDS traffic.
// grid (64 token-blocks, 16 code-splits) x 256 threads; 512 codes per split.
// enc zero-fill fused, metered at 1 float4 store / 4 code iterations.
// ---------------------------------------------------------------------------
__global__ __launch_bounds__(256) void k_search(
    const float* __restrict__ z, const int* __restrict__ mask,
    const float* __restrict__ emb, const float* __restrict__ s_e,
    unsigned long long* __restrict__ packed,
    float* __restrict__ enc_out) {
  const int tid  = threadIdx.x;
  const int lane = tid & 63;
  const int w    = tid >> 6;
  const int T0   = blockIdx.x * 256;
  const int I0   = blockIdx.y * 512;
  const int t    = T0 + w * 64 + lane;
  const int b    = t >> 9;
  const int l    = t & 511;

  // load masked z into registers (lane-contiguous global reads, static indices)
  const int m = mask[t];
  const float* zb = z + (size_t)b * 32768 + l;
  float zr[64];
#pragma unroll
  for (int c = 0; c < 64; ++c) {
    float v = zb[(size_t)c * 512];
    zr[c] = m ? v : 0.0f;
  }

  // s_z: numpy 8-accumulator pairwise sum over masked z (bit-identical to ref)
  float rr[8];
#pragma unroll
  for (int j = 0; j < 8; ++j) rr[j] = __fmul_rn(zr[j], zr[j]);
#pragma unroll
  for (int i = 8; i < 64; i += 8)
#pragma unroll
    for (int j = 0; j < 8; ++j) rr[j] = __fadd_rn(rr[j], __fmul_rn(zr[i + j], zr[i + j]));
  const float sz = __fadd_rn(__fadd_rn(__fadd_rn(rr[0], rr[1]), __fadd_rn(rr[2], rr[3])),
                             __fadd_rn(__fadd_rn(rr[4], rr[5]), __fadd_rn(rr[6], rr[7])));

  float* encb = enc_out + (size_t)T0 * 8192 + I0;
  const float4 zero4 = make_float4(0.f, 0.f, 0.f, 0.f);

  unsigned long long best = ~0ull;

  for (int ii = 0; ii < 512; ++ii) {
    const int i = I0 + ii;
    const float se = s_e[i];                 // wave-uniform -> SGPR
    const float* ep = emb + (size_t)i * 64;  // wave-uniform row -> s_load
    float acc = 0.0f;
#pragma unroll
    for (int k = 0; k < 64; ++k) acc = fmaf(ep[k], zr[k], acc);

    // d = fl(fl(s_z + s_e) - fl(2*dot)); total-order bits; pack (d,idx); min
    float d = __fsub_rn(__fadd_rn(sz, se), __fmul_rn(2.0f, acc));
    unsigned int db = __float_as_uint(d);
    db = ((int)db < 0) ? ~db : (db | 0x80000000u);
    unsigned long long p = ((unsigned long long)db << 32) | (unsigned int)i;
    best = (p < best) ? p : best;

    // metered fused zero-fill of this block's (256 tok x 512 code) enc tile
    if ((ii & 3) == 0) {
      int id  = (ii >> 2) * 256 + tid;       // 0..32767 over the loop
      int row = id >> 7;                     // 0..255
      int c4  = id & 127;                    // 0..127
      *(float4*)(encb + (size_t)row * 8192 + c4 * 4) = zero4;
    }
  }

  atomicMin(&packed[t], best);
}

// ---------------------------------------------------------------------------
// K2: per-token finalize — coalesced. Block = 64 consecutive tokens, 512 thr;
// lane <-> l, wave <-> c-slice. Full-line z reads / z_q writes.
// ---------------------------------------------------------------------------
__global__ __launch_bounds__(512) void k_finalize(
    const float* __restrict__ z, const int* __restrict__ mask,
    const float* __restrict__ emb,
    const unsigned long long* __restrict__ packed,
    float* __restrict__ out_zq, float* __restrict__ out_enc,
    float* __restrict__ out_idx,
    int* __restrict__ hist, float* __restrict__ token_loss) {
  __shared__ float part[8][64];
  const int T0   = blockIdx.x * 64;
  const int lane = threadIdx.x & 63;
  const int w    = threadIdx.x >> 6;
  const int b    = T0 >> 9;
  const int l0   = T0 & 511;
  const int t    = T0 + lane;

  const int idx = (int)(unsigned int)(packed[t] & 0xFFFFFFFFu);

  const float* zb = z      + (size_t)b * 32768 + l0 + lane;
  float*       qb = out_zq + (size_t)b * 32768 + l0 + lane;

  float sq = 0.0f;
#pragma unroll
  for (int cc = 0; cc < 8; ++cc) {
    int c = w * 8 + cc;
    float zv   = zb[(size_t)c * 512];
    float e    = emb[(size_t)idx * 64 + c];
    float diff = __fsub_rn(e, zv);
    qb[(size_t)c * 512] = __fadd_rn(zv, diff);   // z + (z_q - z), bit-exact STE
    sq = fmaf(diff, diff, sq);
  }
  part[w][lane] = sq;
  __syncthreads();

  if (w == 0) {
    float s = __fadd_rn(
        __fadd_rn(__fadd_rn(part[0][lane], part[1][lane]),
                  __fadd_rn(part[2][lane], part[3][lane])),
        __fadd_rn(__fadd_rn(part[4][lane], part[5][lane]),
                  __fadd_rn(part[6][lane], part[7][lane])));
    token_loss[t] = mask[t] ? s : 0.0f;
    out_idx[t] = (float)idx;
    out_enc[(size_t)t * 8192 + idx] = 1.0f;
    atomicAdd(&hist[idx], 1);
  }
}

// ---------------------------------------------------------------------------
// K3a: partial reductions (64 blocks). loss+maskcnt over 256 tokens/block,
// entropy over 128 hist entries/block.
// ---------------------------------------------------------------------------
__global__ __launch_bounds__(256) void k_partial(
    const float* __restrict__ token_loss, const int* __restrict__ mask,
    const int* __restrict__ hist, float* __restrict__ partials) {
  __shared__ float sf[256], sm[256], sh[256];
  const int bb = blockIdx.x, tid = threadIdx.x;
  int ti = bb * 256 + tid;
  sf[tid] = token_loss[ti];
  sm[tid] = (float)mask[ti];
  float h = 0.f;
  if (tid < 128) {
    float pm = (float)hist[bb * 128 + tid] * (1.0f / 16384.0f);
    h = pm * logf(pm + 1e-10f);
  }
  sh[tid] = h;
  __syncthreads();
  for (int off = 128; off; off >>= 1) {
    if (tid < off) { sf[tid] += sf[tid + off]; sm[tid] += sm[tid + off]; sh[tid] += sh[tid + off]; }
    __syncthreads();
  }
  if (tid == 0) {
    partials[bb]       = sf[0];
    partials[64 + bb]  = sm[0];
    partials[128 + bb] = sh[0];
  }
}

// ---------------------------------------------------------------------------
// K3b: final scalars (1 block, 64 threads)
// ---------------------------------------------------------------------------
__global__ __launch_bounds__(64) void k_final(
    const float* __restrict__ partials, float* __restrict__ out) {
  int tn = threadIdx.x;
  float lo = partials[tn], mc = partials[64 + tn], en = partials[128 + tn];
#pragma unroll
  for (int off = 32; off; off >>= 1) {
    lo += __shfl_down(lo, off, 64);
    mc += __shfl_down(mc, off, 64);
    en += __shfl_down(en, off, 64);
  }
  if (tn == 0) {
    float denom = mc * 64.0f;
    float el = lo / denom;                  // embedding_loss == commitment_loss
    out[0]      = __fadd_rn(el, __fmul_rn(0.25f, el));
    out[O_PERP] = expf(-en);
  }
}

// ---------------------------------------------------------------------------
extern "C" void kernel_launch(void* const* d_in, const int* in_sizes, int n_in,
                              void* d_out, int out_size, void* d_ws, size_t ws_size,
                              hipStream_t stream) {
  const float* z    = (const float*)d_in[0];
  const int*   mask = (const int*)d_in[1];
  const float* emb  = (const float*)d_in[2];
  float* out = (float*)d_out;
  char*  ws  = (char*)d_ws;

  unsigned long long* packed = (unsigned long long*)ws;          // 16384 * 8B
  float* s_e        = (float*)(ws + 131072);                     // 8192  * 4B
  int*   hist       = (int*)  (ws + 163840);                     // 8192  * 4B
  float* token_loss = (float*)(ws + 196608);                     // 16384 * 4B
  float* partials   = (float*)(ws + 262144);                     // 192   * 4B

  k_init<<<64, 256, 0, stream>>>(emb, packed, s_e, hist);

  dim3 g1(64, 16, 1);   // 64 token-blocks x 16 code-splits
  k_search<<<g1, 256, 0, stream>>>(z, mask, emb, s_e, packed, out + O_ENC);

  k_finalize<<<256, 512, 0, stream>>>(z, mask, emb, packed,
                                      out + O_ZQ, out + O_ENC, out + O_IDX,
                                      hist, token_loss);

  k_partial<<<64, 256, 0, stream>>>(token_loss, mask, hist, partials);
  k_final<<<1, 64, 0, stream>>>(partials, out);
}